// Round 9
// baseline (243.864 us; speedup 1.0000x reference)
//
#include <hip/hip_runtime.h>
#include <stdint.h>

// ---------------- types ----------------
using f32x4  = __attribute__((ext_vector_type(4))) float;
using short8 = __attribute__((ext_vector_type(8))) short;
using u16x4  = __attribute__((ext_vector_type(4))) unsigned short;

#define MFMA(a, b, c) __builtin_amdgcn_mfma_f32_16x16x32_bf16((a), (b), (c), 0, 0, 0)

#define XDIM 256
#define FDIM 512
#define EPS  1e-6f

// ---- workspace layout (bytes) ----
#define QT_OFF    0u          // [512][256] bf16 = 262144
#define KT_OFF    262144u
#define VT_OFF    524288u
#define CTXT_OFF  786432u     // [32][64 e][64 d] bf16 = 262144
#define PART_OFF  1048576u    // [256*2][4096] f32 = 8 MB

// round-to-nearest-even f32 -> bf16 bits
static __device__ __forceinline__ unsigned short f2bf(float f) {
  unsigned u = __float_as_uint(f);
  unsigned r = u + 0x7FFFu + ((u >> 16) & 1u);
  return (unsigned short)(r >> 16);
}

// ---- A-tile staging (64 rows x 256 f32 per tile, 512 threads) ----
// issue: 8 float4 per thread (row = tid>>3, col-block = (tid&7)*32)
static __device__ __forceinline__ void stage_issue(const float* tile_base, int tid, float4 fv[8]) {
  const float* p = tile_base + (size_t)(tid >> 3) * XDIM + (tid & 7) * 32;
#pragma unroll
  for (int i = 0; i < 8; ++i) fv[i] = *(const float4*)(p + i * 4);
}
// write: cvt to bf16, XOR-swizzled row of [64][512B]
static __device__ __forceinline__ void stage_write(char* A, int tid, const float4 fv[8]) {
  const int row = tid >> 3;
  const int sw = (row & 7) << 4;
  char* dst = A + row * 512;
#pragma unroll
  for (int q = 0; q < 4; ++q) {
    short8 v;
    v[0] = (short)f2bf(fv[2 * q].x);     v[1] = (short)f2bf(fv[2 * q].y);
    v[2] = (short)f2bf(fv[2 * q].z);     v[3] = (short)f2bf(fv[2 * q].w);
    v[4] = (short)f2bf(fv[2 * q + 1].x); v[5] = (short)f2bf(fv[2 * q + 1].y);
    v[6] = (short)f2bf(fv[2 * q + 1].z); v[7] = (short)f2bf(fv[2 * q + 1].w);
    *(short8*)(dst + ((((tid & 7) * 64) + q * 16) ^ sw)) = v;
  }
}

// load one ks-phase (64 k) of a 64-f weight chunk: 8 frags
static __device__ __forceinline__ void load_b(const char* base, int ks, int lr, int lk, short8 b[8]) {
#pragma unroll
  for (int nt = 0; nt < 4; ++nt) {
    const char* r = base + (size_t)(nt * 16 + lr) * 512 + ks * 128 + lk * 16;
    b[nt * 2]     = *(const short8*)(r);
    b[nt * 2 + 1] = *(const short8*)(r + 64);
  }
}

// per-row LayerNorm over a 64-col chunk (1 row-fragment, 4 col-fragments)
static __device__ __forceinline__ void ln4(f32x4 acc[4], const float scl[4], const float bia[4]) {
#pragma unroll
  for (int j = 0; j < 4; ++j) {
    float a0 = acc[0][j], a1 = acc[1][j], a2 = acc[2][j], a3 = acc[3][j];
    float s  = a0 + a1 + a2 + a3;
    float s2 = a0 * a0 + a1 * a1 + a2 * a2 + a3 * a3;
#pragma unroll
    for (int off = 1; off < 16; off <<= 1) {
      s  += __shfl_xor(s, off, 16);
      s2 += __shfl_xor(s2, off, 16);
    }
    const float mu  = s * (1.0f / 64.0f);
    const float var = s2 * (1.0f / 64.0f) - mu * mu;
    const float rs  = rsqrtf(var + EPS);
#pragma unroll
    for (int nt = 0; nt < 4; ++nt) acc[nt][j] = (acc[nt][j] - mu) * rs * scl[nt] + bia[nt];
  }
}

// ---------------- kernel 1: weight transpose/cast prep ----------------
__global__ void prep_weights_kernel(const float* __restrict__ Q, const float* __restrict__ K,
                                    const float* __restrict__ V, const float* __restrict__ ls,
                                    unsigned short* __restrict__ Qt, unsigned short* __restrict__ Kt,
                                    unsigned short* __restrict__ Vt) {
  const int flat = blockIdx.x * 256 + threadIdx.x;
  const int mat = flat >> 17;
  const int rem = flat & 131071;
  const int f = rem & 511;
  const int k = rem >> 9;
  if (mat == 0)      Qt[f * 256 + k] = f2bf(Q[k * 512 + f]);
  else if (mat == 1) Kt[f * 256 + k] = f2bf(K[k * 512 + f]);
  else               Vt[f * 256 + k] = f2bf(V[k * 512 + f] * expf(ls[f]));
}

// ---------------- kernel 2: streaming kv projections + LN + ctx ----------------
// grid 256 (1 block/CU), 512 threads. Block: nb = bid&3 (128-f quarter),
// rb = bid>>2: rows [rb*512, +512) = 8 tiles of 64 rows (one group: g = rb>>1).
// Wave w: wc = w&1 (64-f chunk), wr = w>>1 (16 rows of the tile).
__launch_bounds__(512, 2)
__global__ void kv_ctx_kernel(const float* __restrict__ kv,
                              const unsigned short* __restrict__ Kt,
                              const unsigned short* __restrict__ Vt,
                              const float* __restrict__ lnk_s, const float* __restrict__ lnk_b,
                              const float* __restrict__ lnv_s, const float* __restrict__ lnv_b,
                              float* __restrict__ partials) {
  __shared__ __align__(16) char smem[49152];
  char* Abuf = smem;            // [64][512B] bf16, XOR-swizzled
  char* knT  = smem + 32768;    // [64 d][128B] (64 t half), XOR-swizzled
  char* vnT  = smem + 40960;

  const int tid = threadIdx.x, lane = tid & 63, w = tid >> 6;
  const int wc = w & 1, wr = w >> 1;
  const int bid = blockIdx.x, rb = bid >> 2, nb = bid & 3;
  const int row0 = rb * 512;
  const int lr = lane & 15, lk = lane >> 4;

  // hoisted LN params
  float sk[4], bk_[4], sv[4], bv_[4];
#pragma unroll
  for (int nt = 0; nt < 4; ++nt) {
    sk[nt] = lnk_s[nt * 16 + lr]; bk_[nt] = lnk_b[nt * 16 + lr];
    sv[nt] = lnv_s[nt * 16 + lr]; bv_[nt] = lnv_b[nt * 16 + lr];
  }

  const char* kwb = (const char*)Kt + (size_t)(nb * 128 + wc * 64) * 512;
  const char* vwb = (const char*)Vt + (size_t)(nb * 128 + wc * 64) * 512;

  const f32x4 z4 = {0.f, 0.f, 0.f, 0.f};
  f32x4 cacc[4];
#pragma unroll
  for (int i = 0; i < 4; ++i) cacc[i] = z4;

  // ---- prologue: tile 0 staging + B pipeline fill ----
  float4 fv[8];
  stage_issue(kv + (size_t)row0 * XDIM, tid, fv);
  short8 bK[8], bV[8];
  load_b(kwb, 0, lr, lk, bK);
  load_b(vwb, 0, lr, lk, bV);
  stage_write(Abuf, tid, fv);
  __syncthreads();

  const int arow = wr * 16 + lr;
  const int asw = (arow & 7) << 4;
  const int drow = (w & 3) * 16 + lr;
  const int dsw = (drow & 7) << 4;
  const int tq = w >> 2;

  for (int t = 0; t < 8; ++t) {
    if (t < 7) stage_issue(kv + (size_t)(row0 + (t + 1) * 64) * XDIM, tid, fv);

    // ---- GEMM over k=256, continuous B rotation ----
    f32x4 ak[4], av[4];
#pragma unroll
    for (int i = 0; i < 4; ++i) { ak[i] = z4; av[i] = z4; }
#pragma unroll
    for (int ks = 0; ks < 4; ++ks) {
      const char* ap = Abuf + arow * 512;
      const short8 a0 = *(const short8*)(ap + ((ks * 128 + lk * 16) ^ asw));
      const short8 a1 = *(const short8*)(ap + ((ks * 128 + 64 + lk * 16) ^ asw));
#pragma unroll
      for (int nt = 0; nt < 4; ++nt) {
        ak[nt] = MFMA(a0, bK[nt * 2],     ak[nt]);
        ak[nt] = MFMA(a1, bK[nt * 2 + 1], ak[nt]);
      }
      load_b(kwb, (ks + 1) & 3, lr, lk, bK);
#pragma unroll
      for (int nt = 0; nt < 4; ++nt) {
        av[nt] = MFMA(a0, bV[nt * 2],     av[nt]);
        av[nt] = MFMA(a1, bV[nt * 2 + 1], av[nt]);
      }
      load_b(vwb, (ks + 1) & 3, lr, lk, bV);
    }

    ln4(ak, sk, bk_);
    ln4(av, sv, bv_);

    // ---- ctx: two 64-t half-passes (pass p transposes chunk wc==p) ----
#pragma unroll
    for (int p = 0; p < 2; ++p) {
      __syncthreads();   // B1/B3: A & knT reads of previous phase complete
      if (p == 0 && t < 7) stage_write(Abuf, tid, fv);
      if (wc == p) {
#pragma unroll
        for (int nt = 0; nt < 4; ++nt) {
          const int d = nt * 16 + lr;
          const int boff = d * 128 + ((wr * 32 + lk * 8) ^ ((d & 7) << 4));
          u16x4 pk, pv;
#pragma unroll
          for (int j = 0; j < 4; ++j) { pk[j] = f2bf(ak[nt][j]); pv[j] = f2bf(av[nt][j]); }
          *(u16x4*)(knT + boff) = pk;
          *(u16x4*)(vnT + boff) = pv;
        }
      }
      __syncthreads();   // B2/B4: transpose visible
      const short8 a = *(const short8*)(knT + drow * 128 + ((tq * 64 + lk * 16) ^ dsw));
#pragma unroll
      for (int nt = 0; nt < 4; ++nt) {
        const int e = nt * 16 + lr;
        const short8 b = *(const short8*)(vnT + e * 128 + ((tq * 64 + lk * 16) ^ (((e & 7) << 4))));
        cacc[nt] = MFMA(a, b, cacc[nt]);
      }
    }
  }

  // ---- partials: slot by t-half ----
  float* pout = partials + ((size_t)bid * 2 + tq) * 4096;
#pragma unroll
  for (int nt = 0; nt < 4; ++nt)
#pragma unroll
    for (int j = 0; j < 4; ++j)
      pout[((w & 3) * 16 + lk * 4 + j) * 64 + nt * 16 + lr] = cacc[nt][j];
}

// ---------------- kernel 3: reduce 16 partials/group -> ctxT (bf16, /8192, e-major) ----------
__global__ void reduce_ctx_kernel(const float* __restrict__ partials,
                                  unsigned short* __restrict__ ctxTg) {
  const int bid = blockIdx.x, t = threadIdx.x;
  const int gg = bid >> 3, sl = bid & 7;
  const float* base = partials + (size_t)gg * 16 * 4096;
#pragma unroll
  for (int rep = 0; rep < 2; ++rep) {
    const int idx = sl * 512 + rep * 256 + t;  // idx = d*64 + e
    float acc = 0.f;
#pragma unroll
    for (int p = 0; p < 16; ++p) acc += base[(size_t)p * 4096 + idx];
    const int d = idx >> 6, e = idx & 63;
    ctxTg[(size_t)gg * 4096 + e * 64 + d] = f2bf(acc * (1.0f / 8192.0f));
  }
}

// ---------------- kernel 4: streaming q projection + LN + out ----------------
__launch_bounds__(512, 2)
__global__ void q_out_kernel(const float* __restrict__ x, const unsigned short* __restrict__ Qt,
                             const unsigned short* __restrict__ ctxTg,
                             const float* __restrict__ lnq_s, const float* __restrict__ lnq_b,
                             float* __restrict__ out) {
  __shared__ __align__(16) char smem[60416];
  char* Abuf = smem;            // [64][512B] bf16, XOR-swizzled
  char* ctxT = smem + 32768;    // [64 e][144B]
  char* A2   = smem + 41984;    // [2 wc][64 m][144B] (wave-private sections)

  const int tid = threadIdx.x, lane = tid & 63, w = tid >> 6;
  const int wc = w & 1, wr = w >> 1;
  const int bid = blockIdx.x, rb = bid >> 2, nb = bid & 3;
  const int row0 = rb * 512;
  const int g = rb >> 1;
  const int lr = lane & 15, lk = lane >> 4;

  float sq[4], bq_[4];
#pragma unroll
  for (int nt = 0; nt < 4; ++nt) { sq[nt] = lnq_s[nt * 16 + lr]; bq_[nt] = lnq_b[nt * 16 + lr]; }

  const char* qwb = (const char*)Qt + (size_t)(nb * 128 + wc * 64) * 512;

  // ---- prologue: ctxT + tile 0 + B fill ----
  {
    const unsigned short* src = ctxTg + (size_t)g * 4096 + (tid >> 3) * 64 + (tid & 7) * 8;
    *(short8*)(ctxT + (tid >> 3) * 144 + (tid & 7) * 16) = *(const short8*)src;
  }
  float4 fv[8];
  stage_issue(x + (size_t)row0 * XDIM, tid, fv);
  short8 bQ[8];
  load_b(qwb, 0, lr, lk, bQ);
  stage_write(Abuf, tid, fv);
  __syncthreads();

  const int arow = wr * 16 + lr;
  const int asw = (arow & 7) << 4;
  const f32x4 z4 = {0.f, 0.f, 0.f, 0.f};

  for (int t = 0; t < 8; ++t) {
    if (t < 7) stage_issue(x + (size_t)(row0 + (t + 1) * 64) * XDIM, tid, fv);

    f32x4 acc[4];
#pragma unroll
    for (int i = 0; i < 4; ++i) acc[i] = z4;
#pragma unroll
    for (int ks = 0; ks < 4; ++ks) {
      const char* ap = Abuf + arow * 512;
      const short8 a0 = *(const short8*)(ap + ((ks * 128 + lk * 16) ^ asw));
      const short8 a1 = *(const short8*)(ap + ((ks * 128 + 64 + lk * 16) ^ asw));
#pragma unroll
      for (int nt = 0; nt < 4; ++nt) {
        acc[nt] = MFMA(a0, bQ[nt * 2],     acc[nt]);
        acc[nt] = MFMA(a1, bQ[nt * 2 + 1], acc[nt]);
      }
      load_b(qwb, (ks + 1) & 3, lr, lk, bQ);
    }

    ln4(acc, sq, bq_);

    __syncthreads();                 // B1: all waves done reading Abuf(t)
    if (t < 7) stage_write(Abuf, tid, fv);

    // A2: wave-private transpose (same wave writes then reads -> no barrier)
    char* a2 = A2 + wc * 9216;
#pragma unroll
    for (int nt = 0; nt < 4; ++nt) {
      const int d = nt * 16 + lr;
#pragma unroll
      for (int j = 0; j < 4; ++j) {
        const int m = wr * 16 + lk * 4 + j;
        *(unsigned short*)(a2 + m * 144 + d * 2) = f2bf(acc[nt][j]);
      }
    }

    f32x4 o[4];
#pragma unroll
    for (int i = 0; i < 4; ++i) o[i] = z4;
#pragma unroll
    for (int s = 0; s < 2; ++s) {
      const short8 a = *(const short8*)(a2 + (wr * 16 + lr) * 144 + s * 64 + lk * 16);
#pragma unroll
      for (int nt = 0; nt < 4; ++nt) {
        const short8 b = *(const short8*)(ctxT + (nt * 16 + lr) * 144 + s * 64 + lk * 16);
        o[nt] = MFMA(a, b, o[nt]);
      }
    }

    const int rbase = row0 + t * 64 + wr * 16;
#pragma unroll
    for (int nt = 0; nt < 4; ++nt)
#pragma unroll
      for (int j = 0; j < 4; ++j)
        out[(size_t)(rbase + lk * 4 + j) * FDIM + nb * 128 + wc * 64 + nt * 16 + lr] = o[nt][j];

    __syncthreads();                 // B2: Abuf(t+1) visible before next GEMM
  }
}

// ---------------- launch ----------------
extern "C" void kernel_launch(void* const* d_in, const int* in_sizes, int n_in,
                              void* d_out, int out_size, void* d_ws, size_t ws_size,
                              hipStream_t stream) {
  (void)in_sizes; (void)n_in; (void)out_size; (void)ws_size;
  const float* x     = (const float*)d_in[0];
  const float* kv    = (const float*)d_in[1];
  const float* Q     = (const float*)d_in[2];
  const float* K     = (const float*)d_in[3];
  const float* V     = (const float*)d_in[4];
  const float* ls    = (const float*)d_in[5];
  const float* lnq_s = (const float*)d_in[6];
  const float* lnq_b = (const float*)d_in[7];
  const float* lnk_s = (const float*)d_in[8];
  const float* lnk_b = (const float*)d_in[9];
  const float* lnv_s = (const float*)d_in[10];
  const float* lnv_b = (const float*)d_in[11];
  float* out = (float*)d_out;

  char* ws = (char*)d_ws;
  unsigned short* Qt   = (unsigned short*)(ws + QT_OFF);
  unsigned short* Kt   = (unsigned short*)(ws + KT_OFF);
  unsigned short* Vt   = (unsigned short*)(ws + VT_OFF);
  unsigned short* ctxT = (unsigned short*)(ws + CTXT_OFF);
  float* partials      = (float*)(ws + PART_OFF);

  prep_weights_kernel<<<1536, 256, 0, stream>>>(Q, K, V, ls, Qt, Kt, Vt);
  kv_ctx_kernel<<<256, 512, 0, stream>>>(kv, Kt, Vt, lnk_s, lnk_b, lnv_s, lnv_b, partials);
  reduce_ctx_kernel<<<256, 256, 0, stream>>>(partials, ctxT);
  q_out_kernel<<<256, 512, 0, stream>>>(x, Qt, ctxT, lnq_s, lnq_b, out);
}